// Round 5
// baseline (645.624 us; speedup 1.0000x reference)
//
#include <hip/hip_runtime.h>
#include <math.h>

// Problem constants: B=1, T=384, C=512, H=8, D=64, E=16. Inputs/outputs f32.
#define TT 384
#define CC 512
#define HH 8
#define EE 16
#define GRID 512   // 2 blocks/CU on 256 CUs; __launch_bounds__(256,2) guarantees
                   // >=2 resident blocks/CU so all 512 are co-resident (barrier-safe)

typedef __bf16 bf16_t;
typedef __bf16 bf16x8 __attribute__((ext_vector_type(8)));
typedef __bf16 bf16x4v __attribute__((ext_vector_type(4)));
typedef float f32x4 __attribute__((ext_vector_type(4)));

struct Args {
  const float* x; const int* bm;
  const float *ln1w, *ln1b, *wattnb, *wprojb, *abemb, *eemb;
  const float *wekw, *wekb, *wevw, *wevb, *ln2w, *ln2b, *cfcb, *cprojb;
  const float *wattn, *wproj, *cfcw, *cprojw;      // f32 weights (pre-converted P1)
  float *ektab, *evtab, *x1, *out;
  bf16_t *hbuf, *qkv, *ybuf, *h2, *gbuf;
  bf16_t *wattn_bf, *wproj_bf, *cfc_bf, *cproj_bf;
  unsigned* bar;
};

struct SharedG { float part[4][32][32]; };                       // 16384 B
struct SharedA {
  float s[TT]; int ebuf[TT]; float qe[EE][68]; float evh[EE * 64];
  float red[256]; float absh[EE]; float scr[8];
};                                                               // 12640 B
union SharedU { SharedG g; SharedA a; float sh[8]; };

__device__ __forceinline__ float wave_reduce_sum(float v) {
#pragma unroll
  for (int off = 32; off >= 1; off >>= 1) v += __shfl_xor(v, off, 64);
  return v;
}
__device__ __forceinline__ float wave_reduce_max(float v) {
#pragma unroll
  for (int off = 32; off >= 1; off >>= 1) v = fmaxf(v, __shfl_xor(v, off, 64));
  return v;
}

// Device-scope grid barrier. Counter slots zeroed by hipMemsetAsync each launch.
__device__ __forceinline__ void gbar(unsigned* c) {
  __syncthreads();
  if (threadIdx.x == 0) {
    __threadfence();
    __hip_atomic_fetch_add(c, 1u, __ATOMIC_ACQ_REL, __HIP_MEMORY_SCOPE_AGENT);
    while (__hip_atomic_load(c, __ATOMIC_ACQUIRE, __HIP_MEMORY_SCOPE_AGENT) <
           (unsigned)GRID)
      __builtin_amdgcn_s_sleep(2);
    __threadfence();
  }
  __syncthreads();
}

// ---- LayerNorm row (f32 in, bf16 out), whole block -------------------------
__device__ void ln_row(const float* __restrict__ xin, const float* __restrict__ w,
                       const float* __restrict__ b, bf16_t* __restrict__ out,
                       int row, SharedU& su) {
  int tid = threadIdx.x;
  __syncthreads();
  const float* xr = xin + (size_t)row * CC;
  float v0 = xr[tid], v1 = xr[tid + 256];
  float s = wave_reduce_sum(v0 + v1);
  float q = wave_reduce_sum(v0 * v0 + v1 * v1);
  int wv_ = tid >> 6, ln_ = tid & 63;
  if (ln_ == 0) { su.sh[wv_] = s; su.sh[4 + wv_] = q; }
  __syncthreads();
  float stot = su.sh[0] + su.sh[1] + su.sh[2] + su.sh[3];
  float qtot = su.sh[4] + su.sh[5] + su.sh[6] + su.sh[7];
  float mu = stot * (1.0f / 512.0f);
  float var = qtot * (1.0f / 512.0f) - mu * mu;
  float rs = rsqrtf(var + 1e-5f);
  out[(size_t)row * CC + tid] = (bf16_t)((v0 - mu) * rs * w[tid] + b[tid]);
  out[(size_t)row * CC + tid + 256] =
      (bf16_t)((v1 - mu) * rs * w[tid + 256] + b[tid + 256]);
}

// ---- edge-table block unit (4 wave-units of 16 outputs) --------------------
__device__ void table_unit(int idx, const Args& A) {
  int tid = threadIdx.x, lane = tid & 63;
  int wid = idx * 4 + (tid >> 6);  // 0..1023
  int gbase = wid * 16;
  int table = gbase >> 13;
  int e = (gbase >> 9) & 15;
  int c0 = gbase & 511;
  const float* er = A.eemb + e * 512 + lane * 8;
  f32x4 ea = *(const f32x4*)er;
  f32x4 eb = *(const f32x4*)(er + 4);
  const float* wbase = table ? A.wevw : A.wekw;
  const float* bbase = table ? A.wevb : A.wekb;
  float* obase = (table ? A.evtab : A.ektab) + e * 512;
#pragma unroll
  for (int o = 0; o < 16; o++) {
    int c = c0 + o;
    const float* wr = wbase + (size_t)c * 512 + lane * 8;
    f32x4 wa = *(const f32x4*)wr;
    f32x4 wb = *(const f32x4*)(wr + 4);
    float acc = ea.x * wa.x + ea.y * wa.y + ea.z * wa.z + ea.w * wa.w +
                eb.x * wb.x + eb.y * wb.y + eb.z * wb.z + eb.w * wb.w;
    acc = wave_reduce_sum(acc);
    if (lane == 0) obase[c] = acc + bbase[c];
  }
}

// ---- split-K 32x32 GEMM tile: C=A@W^T+bias (A,W bf16; epilogue per MODE) ---
// MODE 0: ->bf16  1: gelu->bf16  2: +res->f32  3: +res->f32(out)
template <int MODE>
__device__ void gemm_tile(const bf16_t* __restrict__ Abase,
                          const bf16_t* __restrict__ Wb,
                          const float* __restrict__ bias,
                          const float* __restrict__ res, void* __restrict__ out,
                          int N, int K, int m0, int n0, SharedU& su) {
  int tid = threadIdx.x, lane = tid & 63, wave = tid >> 6;
  int r16 = lane & 15, quad = lane >> 4;
  int kchunk = K >> 2, k0 = wave * kchunk;

  f32x4 acc[2][2];
  f32x4 zero = {0.f, 0.f, 0.f, 0.f};
#pragma unroll
  for (int i = 0; i < 2; i++)
#pragma unroll
    for (int j = 0; j < 2; j++) acc[i][j] = zero;

  const bf16_t* Ap = Abase + (size_t)(m0 + r16) * K + k0 + quad * 8;
  const bf16_t* Wp = Wb + (size_t)(n0 + r16) * K + k0 + quad * 8;
  for (int kb = 0; kb < kchunk; kb += 32) {
    bf16x8 af[2], bfr[2];
#pragma unroll
    for (int t = 0; t < 2; t++)
      af[t] = *(const bf16x8*)(Ap + (size_t)t * 16 * K + kb);
#pragma unroll
    for (int t = 0; t < 2; t++)
      bfr[t] = *(const bf16x8*)(Wp + (size_t)t * 16 * K + kb);
#pragma unroll
    for (int i = 0; i < 2; i++)
#pragma unroll
      for (int j = 0; j < 2; j++)
        acc[i][j] = __builtin_amdgcn_mfma_f32_16x16x32_bf16(af[i], bfr[j],
                                                            acc[i][j], 0, 0, 0);
  }

  __syncthreads();  // protect LDS reuse across units/phases
#pragma unroll
  for (int i = 0; i < 2; i++)
#pragma unroll
    for (int j = 0; j < 2; j++)
#pragma unroll
      for (int r = 0; r < 4; r++)
        su.g.part[wave][i * 16 + quad * 4 + r][j * 16 + r16] = acc[i][j][r];
  __syncthreads();

  int row = tid >> 3, c4 = (tid & 7) * 4;
  f32x4 v = *(const f32x4*)&su.g.part[0][row][c4];
  v += *(const f32x4*)&su.g.part[1][row][c4];
  v += *(const f32x4*)&su.g.part[2][row][c4];
  v += *(const f32x4*)&su.g.part[3][row][c4];
  int grow = m0 + row, gcol = n0 + c4;
  v += *(const f32x4*)(bias + gcol);
  if (MODE == 1) {
#pragma unroll
    for (int t = 0; t < 4; t++)
      v[t] = 0.5f * v[t] * (1.0f + erff(v[t] * 0.70710678118654752f));
  }
  if (MODE == 2 || MODE == 3) {
    v += *(const f32x4*)(res + (size_t)grow * N + gcol);
    *(f32x4*)((float*)out + (size_t)grow * N + gcol) = v;
  } else {
    bf16x4v o;
#pragma unroll
    for (int t = 0; t < 4; t++) o[t] = (bf16_t)v[t];
    *(bf16x4v*)((bf16_t*)out + (size_t)grow * N + gcol) = o;
  }
}

// ---- attention for one (i,h): whole block ----------------------------------
__device__ void attn_one(int i, int h, const Args& A, SharedU& su) {
  SharedA& sa = su.a;
  int tid = threadIdx.x, lane = tid & 63, wave = tid >> 6;
  int n = i + 1;
  __syncthreads();  // LDS reuse guard

  for (int j = tid; j < n; j += 256) sa.ebuf[j] = A.bm[i * TT + j];
  if (tid < EE) sa.absh[tid] = A.abemb[tid * HH + h];
  for (int idx = tid; idx < EE * 64; idx += 256) {
    int e = idx >> 6, d = idx & 63;
    float qv = (float)A.qkv[(size_t)i * 1536 + h * 64 + d];
    sa.qe[e][d] = qv * A.ektab[e * 512 + h * 64 + d];
    sa.evh[idx] = A.evtab[e * 512 + h * 64 + d];
  }
  __syncthreads();

  // scores: lane per j, direct global K reads (L2-resident)
  for (int jl = tid; jl < n; jl += 256) {
    int e = sa.ebuf[jl];
    const uint4* kp = (const uint4*)(A.qkv + (size_t)jl * 1536 + 512 + h * 64);
    uint4 kr[8];
#pragma unroll
    for (int dg = 0; dg < 8; dg++) kr[dg] = kp[dg];
    float acc = 0.f;
#pragma unroll
    for (int dg = 0; dg < 8; dg++) {
      bf16x8 kv = *reinterpret_cast<const bf16x8*>(&kr[dg]);
      f32x4 qa = *(const f32x4*)&sa.qe[e][dg * 8];
      f32x4 qb = *(const f32x4*)&sa.qe[e][dg * 8 + 4];
      acc += (float)kv[0] * qa.x + (float)kv[1] * qa.y + (float)kv[2] * qa.z +
             (float)kv[3] * qa.w + (float)kv[4] * qb.x + (float)kv[5] * qb.y +
             (float)kv[6] * qb.z + (float)kv[7] * qb.w;
    }
    sa.s[jl] = acc * 0.125f + sa.absh[e];
  }
  __syncthreads();

  // softmax
  float lm = -1e30f;
  for (int j = tid; j < n; j += 256) lm = fmaxf(lm, sa.s[j]);
  lm = wave_reduce_max(lm);
  if (lane == 0) sa.scr[wave] = lm;
  __syncthreads();
  float mx = fmaxf(fmaxf(sa.scr[0], sa.scr[1]), fmaxf(sa.scr[2], sa.scr[3]));
  float ls = 0.0f;
  for (int j = tid; j < n; j += 256) {
    float p = __expf(sa.s[j] - mx);
    sa.s[j] = p;
    ls += p;
  }
  ls = wave_reduce_sum(ls);
  if (lane == 0) sa.scr[4 + wave] = ls;
  __syncthreads();
  float inv = 1.0f / (sa.scr[4] + sa.scr[5] + sa.scr[6] + sa.scr[7]);

  // PV: wave per j, lane per d
  float acc = 0.0f;
  int j = wave;
  for (; j + 4 < n; j += 8) {
    int e0 = sa.ebuf[j], e1 = sa.ebuf[j + 4];
    float p0 = sa.s[j], p1 = sa.s[j + 4];
    float v0 = (float)A.qkv[(size_t)j * 1536 + 1024 + h * 64 + lane];
    float v1 = (float)A.qkv[(size_t)(j + 4) * 1536 + 1024 + h * 64 + lane];
    acc += p0 * v0 * sa.evh[e0 * 64 + lane] + p1 * v1 * sa.evh[e1 * 64 + lane];
  }
  for (; j < n; j += 4) {
    int e = sa.ebuf[j];
    float vv = (float)A.qkv[(size_t)j * 1536 + 1024 + h * 64 + lane];
    acc += sa.s[j] * vv * sa.evh[e * 64 + lane];
  }
  sa.red[wave * 64 + lane] = acc;
  __syncthreads();
  if (tid < 64) {
    float y = (sa.red[tid] + sa.red[64 + tid] + sa.red[128 + tid] +
               sa.red[192 + tid]) * inv;
    A.ybuf[(size_t)i * CC + h * 64 + tid] = (bf16_t)y;
  }
}

// ---------------------------------------------------------------------------
__global__ __launch_bounds__(256, 2) void fused_k(Args A) {
  __shared__ SharedU su;
  int bid = blockIdx.x, tid = threadIdx.x;

  // ---- P1: edge tables (units 0..255) + LN1 (units 256..639) + w->bf16 conv
  for (int u = bid; u < 640; u += GRID) {
    if (u < 256) table_unit(u, A);
    else ln_row(A.x, A.ln1w, A.ln1b, A.hbuf, u - 256, su);
  }
  {  // convert 4 GEMM weight matrices to bf16 (786432 f32x4 units)
    int g = bid * 256 + tid;
    for (int v = g; v < 786432; v += GRID * 256) {
      const float* src; bf16_t* dst; int loc;
      if (v < 196608)      { src = A.wattn;  dst = A.wattn_bf; loc = v; }
      else if (v < 262144) { src = A.wproj;  dst = A.wproj_bf; loc = v - 196608; }
      else if (v < 524288) { src = A.cfcw;   dst = A.cfc_bf;   loc = v - 262144; }
      else                 { src = A.cprojw; dst = A.cproj_bf; loc = v - 524288; }
      f32x4 a = *((const f32x4*)src + loc);
      bf16x4v o;
      o[0] = (bf16_t)a.x; o[1] = (bf16_t)a.y; o[2] = (bf16_t)a.z; o[3] = (bf16_t)a.w;
      *((bf16x4v*)dst + loc) = o;
    }
  }
  gbar(A.bar + 0);

  // ---- P2: QKV = h @ w_attn^T + b (384x1536, K=512): 576 tiles
  for (int u = bid; u < 576; u += GRID)
    gemm_tile<0>(A.hbuf, A.wattn_bf, A.wattnb, nullptr, A.qkv, 1536, 512,
                 (u / 48) * 32, (u % 48) * 32, su);
  gbar(A.bar + 1);

  // ---- P3: attention, 1536 pair-units (p, 383-p) x 8 heads — equal cost
  for (int u = bid; u < 1536; u += GRID) {
    int p = u >> 3, h = u & 7;
    attn_one(p, h, A, su);
    attn_one(383 - p, h, A, su);
  }
  gbar(A.bar + 2);

  // ---- P4: x1 = x + y @ w_proj^T + b (384x512, K=512): 192 tiles
  for (int u = bid; u < 192; u += GRID)
    gemm_tile<2>(A.ybuf, A.wproj_bf, A.wprojb, A.x, A.x1, 512, 512,
                 (u / 16) * 32, (u % 16) * 32, su);
  gbar(A.bar + 3);

  // ---- P5: LN2 (384 rows)
  for (int u = bid; u < 384; u += GRID)
    ln_row(A.x1, A.ln2w, A.ln2b, A.h2, u, su);
  gbar(A.bar + 4);

  // ---- P6: fc + gelu (384x2048, K=512): 768 tiles
  for (int u = bid; u < 768; u += GRID)
    gemm_tile<1>(A.h2, A.cfc_bf, A.cfcb, nullptr, A.gbuf, 2048, 512,
                 (u / 64) * 32, (u % 64) * 32, su);
  gbar(A.bar + 5);

  // ---- P7: out = x1 + g @ c_proj^T + b (384x512, K=2048): 192 tiles
  for (int u = bid; u < 192; u += GRID)
    gemm_tile<3>(A.gbuf, A.cproj_bf, A.cprojb, A.x1, A.out, 512, 2048,
                 (u / 16) * 32, (u % 16) * 32, su);
}

// ---------------------------------------------------------------------------
extern "C" void kernel_launch(void* const* d_in, const int* in_sizes, int n_in,
                              void* d_out, int out_size, void* d_ws,
                              size_t ws_size, hipStream_t stream) {
  Args A;
  A.x = (const float*)d_in[0];
  A.bm = (const int*)d_in[1];
  A.ln1w = (const float*)d_in[2];
  A.ln1b = (const float*)d_in[3];
  A.wattn = (const float*)d_in[4];
  A.wattnb = (const float*)d_in[5];
  A.wproj = (const float*)d_in[6];
  A.wprojb = (const float*)d_in[7];
  A.abemb = (const float*)d_in[8];
  A.eemb = (const float*)d_in[9];
  A.wekw = (const float*)d_in[10];
  A.wekb = (const float*)d_in[11];
  A.wevw = (const float*)d_in[12];
  A.wevb = (const float*)d_in[13];
  A.ln2w = (const float*)d_in[14];
  A.ln2b = (const float*)d_in[15];
  A.cfcw = (const float*)d_in[16];
  A.cfcb = (const float*)d_in[17];
  A.cprojw = (const float*)d_in[18];
  A.cprojb = (const float*)d_in[19];
  A.out = (float*)d_out;

  char* wp = (char*)d_ws;
  A.ektab = (float*)wp;    wp += 16 * 512 * 4;
  A.evtab = (float*)wp;    wp += 16 * 512 * 4;
  A.x1 = (float*)wp;       wp += 384 * 512 * 4;
  A.hbuf = (bf16_t*)wp;    wp += 384 * 512 * 2;
  A.qkv = (bf16_t*)wp;     wp += 384 * 1536 * 2;
  A.ybuf = (bf16_t*)wp;    wp += 384 * 512 * 2;
  A.h2 = (bf16_t*)wp;      wp += 384 * 512 * 2;
  A.gbuf = (bf16_t*)wp;    wp += 384 * 2048 * 2;
  A.wattn_bf = (bf16_t*)wp; wp += 1536 * 512 * 2;
  A.wproj_bf = (bf16_t*)wp; wp += 512 * 512 * 2;
  A.cfc_bf = (bf16_t*)wp;   wp += 2048 * 512 * 2;
  A.cproj_bf = (bf16_t*)wp; wp += 512 * 2048 * 2;
  A.bar = (unsigned*)wp;    wp += 64;

  hipMemsetAsync(A.bar, 0, 64, stream);
  fused_k<<<GRID, 256, 0, stream>>>(A);
}

// Round 6
// 176.993 us; speedup vs baseline: 3.6477x; 3.6477x over previous
//
#include <hip/hip_runtime.h>
#include <math.h>

// Problem constants: B=1, T=384, C=512, H=8, D=64, E=16. Inputs/outputs f32.
#define TT 384
#define CC 512
#define HH 8
#define EE 16

typedef __bf16 bf16_t;
typedef __bf16 bf16x8 __attribute__((ext_vector_type(8)));
typedef __bf16 bf16x4v __attribute__((ext_vector_type(4)));
typedef float f32x4 __attribute__((ext_vector_type(4)));

__device__ __forceinline__ float wave_reduce_sum(float v) {
#pragma unroll
  for (int off = 32; off >= 1; off >>= 1) v += __shfl_xor(v, off, 64);
  return v;
}
__device__ __forceinline__ float wave_reduce_max(float v) {
#pragma unroll
  for (int off = 32; off >= 1; off >>= 1) v = fmaxf(v, __shfl_xor(v, off, 64));
  return v;
}

// ---------------------------------------------------------------------------
// pre_k: everything input-only, one dispatch, 1569 blocks:
//  [0,256)     edge tables ek/ev (wave-unit = 16 outputs)
//  [256,640)   qkv W' rows:  wqkv_bf[n] = ln1w∘wattn[n] (bf16), s1q[n], cq[n]
//  [640,1152)  fc  W' rows:  wfc_bf[n]  = ln2w∘cfcw[n],  s1f[n], cf[n]
//  [1152,1216) proj weight f32->bf16 (plain)
//  [1216,1472) cproj weight f32->bf16 (plain)
//  [1472,1568) x row stats -> xmu, xrs
//  [1568]      zero x1 stats accumulators
// ---------------------------------------------------------------------------
struct PreArgs {
  const float *x, *ln1w, *ln1b, *wattn, *wattnb, *eemb, *wekw, *wekb, *wevw,
      *wevb, *ln2w, *ln2b, *cfcw, *cfcb, *wproj, *wcproj;
  float *ektab, *evtab, *xmu, *xrs, *x1s1, *x1s2, *s1q, *cq, *s1f, *cf;
  bf16_t *wqkv_bf, *wfc_bf, *wproj_bf, *wcproj_bf;
};

__device__ __forceinline__ void wrow_unit(const float* __restrict__ wr,
                                          const float* __restrict__ g,
                                          const float* __restrict__ bb,
                                          float extra_c, bf16_t* __restrict__ orow,
                                          float* __restrict__ s1p,
                                          float* __restrict__ cp, int lane) {
  const float* p = wr + lane * 8;
  f32x4 w0 = *(const f32x4*)p, w1 = *(const f32x4*)(p + 4);
  f32x4 g0 = *(const f32x4*)(g + lane * 8), g1 = *(const f32x4*)(g + lane * 8 + 4);
  f32x4 b0 = *(const f32x4*)(bb + lane * 8), b1 = *(const f32x4*)(bb + lane * 8 + 4);
  f32x4 p0 = w0 * g0, p1 = w1 * g1;
  bf16x8 o;
  o[0] = (bf16_t)p0.x; o[1] = (bf16_t)p0.y; o[2] = (bf16_t)p0.z; o[3] = (bf16_t)p0.w;
  o[4] = (bf16_t)p1.x; o[5] = (bf16_t)p1.y; o[6] = (bf16_t)p1.z; o[7] = (bf16_t)p1.w;
  *(bf16x8*)(orow + lane * 8) = o;
  float s1 = p0.x + p0.y + p0.z + p0.w + p1.x + p1.y + p1.z + p1.w;
  float c = w0.x * b0.x + w0.y * b0.y + w0.z * b0.z + w0.w * b0.w +
            w1.x * b1.x + w1.y * b1.y + w1.z * b1.z + w1.w * b1.w;
  s1 = wave_reduce_sum(s1);
  c = wave_reduce_sum(c);
  if (lane == 0) { *s1p = s1; *cp = c + extra_c; }
}

__global__ __launch_bounds__(256) void pre_k(PreArgs P) {
  int b = blockIdx.x, tid = threadIdx.x, lane = tid & 63, wave = tid >> 6;
  if (b < 256) {
    // ---- edge tables: wave per 16 outputs
    int wid = b * 4 + wave;  // 0..1023
    int gbase = wid * 16;
    int table = gbase >> 13;
    int e = (gbase >> 9) & 15;
    int c0 = gbase & 511;
    const float* er = P.eemb + e * 512 + lane * 8;
    f32x4 ea = *(const f32x4*)er;
    f32x4 eb = *(const f32x4*)(er + 4);
    const float* wbase = table ? P.wevw : P.wekw;
    const float* bbase = table ? P.wevb : P.wekb;
    float* obase = (table ? P.evtab : P.ektab) + e * 512;
#pragma unroll
    for (int o = 0; o < 16; o++) {
      int c = c0 + o;
      const float* wr = wbase + (size_t)c * 512 + lane * 8;
      f32x4 wa = *(const f32x4*)wr;
      f32x4 wb = *(const f32x4*)(wr + 4);
      float acc = ea.x * wa.x + ea.y * wa.y + ea.z * wa.z + ea.w * wa.w +
                  eb.x * wb.x + eb.y * wb.y + eb.z * wb.z + eb.w * wb.w;
      acc = wave_reduce_sum(acc);
      if (lane == 0) obase[c] = acc + bbase[c];
    }
  } else if (b < 640) {
    int n = (b - 256) * 4 + wave;  // 0..1535
    wrow_unit(P.wattn + (size_t)n * 512, P.ln1w, P.ln1b, P.wattnb[n],
              P.wqkv_bf + (size_t)n * 512, P.s1q + n, P.cq + n, lane);
  } else if (b < 1152) {
    int n = (b - 640) * 4 + wave;  // 0..2047
    wrow_unit(P.cfcw + (size_t)n * 512, P.ln2w, P.ln2b, P.cfcb[n],
              P.wfc_bf + (size_t)n * 512, P.s1f + n, P.cf + n, lane);
  } else if (b < 1216) {
    // proj conv: 65536 f32x4 units over 64 blocks
    int base = (b - 1152) * 1024;
    for (int u = tid; u < 1024; u += 256) {
      f32x4 a = *((const f32x4*)P.wproj + base + u);
      bf16x4v o;
      o[0] = (bf16_t)a.x; o[1] = (bf16_t)a.y; o[2] = (bf16_t)a.z; o[3] = (bf16_t)a.w;
      *((bf16x4v*)P.wproj_bf + base + u) = o;
    }
  } else if (b < 1472) {
    // cproj conv: 262144 f32x4 units over 256 blocks
    int base = (b - 1216) * 1024;
    for (int u = tid; u < 1024; u += 256) {
      f32x4 a = *((const f32x4*)P.wcproj + base + u);
      bf16x4v o;
      o[0] = (bf16_t)a.x; o[1] = (bf16_t)a.y; o[2] = (bf16_t)a.z; o[3] = (bf16_t)a.w;
      *((bf16x4v*)P.wcproj_bf + base + u) = o;
    }
  } else if (b < 1568) {
    // x row stats: wave per row
    int r = (b - 1472) * 4 + wave;  // 0..383
    const float* xr = P.x + (size_t)r * 512 + lane * 8;
    f32x4 a = *(const f32x4*)xr, c = *(const f32x4*)(xr + 4);
    float s = a.x + a.y + a.z + a.w + c.x + c.y + c.z + c.w;
    float q = a.x * a.x + a.y * a.y + a.z * a.z + a.w * a.w +
              c.x * c.x + c.y * c.y + c.z * c.z + c.w * c.w;
    s = wave_reduce_sum(s);
    q = wave_reduce_sum(q);
    if (lane == 0) {
      float mu = s * (1.0f / 512.0f);
      float var = q * (1.0f / 512.0f) - mu * mu;
      P.xmu[r] = mu;
      P.xrs[r] = rsqrtf(var + 1e-5f);
    }
  } else {
    for (int i = tid; i < 384; i += 256) { P.x1s1[i] = 0.f; P.x1s2[i] = 0.f; }
  }
}

// ---------------------------------------------------------------------------
// Split-K NT GEMM, 32x32 tile, 4 waves each K/4. MFMA 16x16x32 bf16.
// A/B frag: row=lane&15, k=(lane>>4)*8+j ; C/D: col=lane&15, row=(lane>>4)*4+r
// MODE 0 (QKV): A=x f32, W=wqkv_bf; v = rs_r*(acc - mu_r*s1[c]) + cc[c] ->bf16
// MODE 1 (PROJ): A bf16, +bias +res ->f32, atomic row stats of result
// MODE 2 (FC):   A=x1 f32, stats S1/S2; affine; gelu ->bf16
// MODE 3 (CPROJ):A bf16, +bias +res ->f32 (d_out)
// ---------------------------------------------------------------------------
template <int MODE>
__global__ __launch_bounds__(256) void gemm_k(
    const void* __restrict__ Aptr, const bf16_t* __restrict__ Wb,
    const float* __restrict__ e0, const float* __restrict__ e1,
    const float* __restrict__ e2, const float* __restrict__ e3,
    const float* __restrict__ res, void* __restrict__ out,
    float* __restrict__ st1, float* __restrict__ st2, int N, int K) {
  constexpr bool AF32 = (MODE == 0 || MODE == 2);
  __shared__ float part[4][32][32];
  int tid = threadIdx.x, lane = tid & 63, wave = tid >> 6;
  int m0 = blockIdx.y * 32, n0 = blockIdx.x * 32;
  int r16 = lane & 15, quad = lane >> 4;
  int kchunk = K >> 2, k0 = wave * kchunk;

  f32x4 acc[2][2];
  f32x4 zero = {0.f, 0.f, 0.f, 0.f};
#pragma unroll
  for (int i = 0; i < 2; i++)
#pragma unroll
    for (int j = 0; j < 2; j++) acc[i][j] = zero;

  const float* Af = (const float*)Aptr + (size_t)(m0 + r16) * K + k0 + quad * 8;
  const bf16_t* Ab = (const bf16_t*)Aptr + (size_t)(m0 + r16) * K + k0 + quad * 8;
  const bf16_t* Wp = Wb + (size_t)(n0 + r16) * K + k0 + quad * 8;
  for (int kb = 0; kb < kchunk; kb += 32) {
    bf16x8 af[2], bfr[2];
#pragma unroll
    for (int t = 0; t < 2; t++) {
      if (AF32) {
        f32x4 a = *(const f32x4*)(Af + (size_t)t * 16 * K + kb);
        f32x4 c = *(const f32x4*)(Af + (size_t)t * 16 * K + kb + 4);
        af[t][0] = (bf16_t)a.x; af[t][1] = (bf16_t)a.y;
        af[t][2] = (bf16_t)a.z; af[t][3] = (bf16_t)a.w;
        af[t][4] = (bf16_t)c.x; af[t][5] = (bf16_t)c.y;
        af[t][6] = (bf16_t)c.z; af[t][7] = (bf16_t)c.w;
      } else {
        af[t] = *(const bf16x8*)(Ab + (size_t)t * 16 * K + kb);
      }
    }
#pragma unroll
    for (int t = 0; t < 2; t++)
      bfr[t] = *(const bf16x8*)(Wp + (size_t)t * 16 * K + kb);
#pragma unroll
    for (int i = 0; i < 2; i++)
#pragma unroll
      for (int j = 0; j < 2; j++)
        acc[i][j] = __builtin_amdgcn_mfma_f32_16x16x32_bf16(af[i], bfr[j],
                                                            acc[i][j], 0, 0, 0);
  }

#pragma unroll
  for (int i = 0; i < 2; i++)
#pragma unroll
    for (int j = 0; j < 2; j++)
#pragma unroll
      for (int r = 0; r < 4; r++)
        part[wave][i * 16 + quad * 4 + r][j * 16 + r16] = acc[i][j][r];
  __syncthreads();

  int row = tid >> 3, c4 = (tid & 7) * 4;
  f32x4 v = *(const f32x4*)&part[0][row][c4];
  v += *(const f32x4*)&part[1][row][c4];
  v += *(const f32x4*)&part[2][row][c4];
  v += *(const f32x4*)&part[3][row][c4];
  int grow = m0 + row, gcol = n0 + c4;

  if (MODE == 0 || MODE == 2) {
    float mu, rs;
    if (MODE == 0) {
      mu = e0[grow]; rs = e1[grow];
    } else {
      float S = e0[grow], Q = e1[grow];
      mu = S * (1.0f / 512.0f);
      float var = Q * (1.0f / 512.0f) - mu * mu;
      rs = rsqrtf(var + 1e-5f);
    }
    f32x4 s1v = *(const f32x4*)(e2 + gcol);
    f32x4 ccv = *(const f32x4*)(e3 + gcol);
#pragma unroll
    for (int t = 0; t < 4; t++) {
      float x = rs * (v[t] - mu * s1v[t]) + ccv[t];
      if (MODE == 2) x = 0.5f * x * (1.0f + erff(x * 0.70710678118654752f));
      v[t] = x;
    }
    bf16x4v o;
#pragma unroll
    for (int t = 0; t < 4; t++) o[t] = (bf16_t)v[t];
    *(bf16x4v*)((bf16_t*)out + (size_t)grow * N + gcol) = o;
  } else {
    v += *(const f32x4*)(e2 + gcol);  // bias
    v += *(const f32x4*)(res + (size_t)grow * N + gcol);
    *(f32x4*)((float*)out + (size_t)grow * N + gcol) = v;
    if (MODE == 1) {
      float sv = v.x + v.y + v.z + v.w;
      float qv = v.x * v.x + v.y * v.y + v.z * v.z + v.w * v.w;
      sv += __shfl_down(sv, 4, 8); qv += __shfl_down(qv, 4, 8);
      sv += __shfl_down(sv, 2, 8); qv += __shfl_down(qv, 2, 8);
      sv += __shfl_down(sv, 1, 8); qv += __shfl_down(qv, 1, 8);
      if ((tid & 7) == 0) {
        atomicAdd(st1 + grow, sv);
        atomicAdd(st2 + grow, qv);
      }
    }
  }
}

// ---------------------------------------------------------------------------
// Attention: one block per (query row i, head h). 256 thr = 4 waves.
// scores: lane-per-j, direct global K reads (L2-resident). PV: wave-per-j.
// ---------------------------------------------------------------------------
__global__ __launch_bounds__(256) void attn_k(
    const bf16_t* __restrict__ qkv, const int* __restrict__ bias_matrix,
    const float* __restrict__ attn_bias_emb, const float* __restrict__ ek_tab,
    const float* __restrict__ ev_tab, bf16_t* __restrict__ ybuf) {
  __shared__ float s[TT];
  __shared__ int ebuf[TT];
  __shared__ float qe[EE][68];
  __shared__ float evh[EE * 64];
  __shared__ float red[4 * 64];
  __shared__ float absh[EE];
  __shared__ float scr[8];

  int i = blockIdx.x, h = blockIdx.y;
  int tid = threadIdx.x, lane = tid & 63, wave = tid >> 6;
  int n = i + 1;

  for (int j = tid; j < n; j += 256) ebuf[j] = bias_matrix[i * TT + j];
  if (tid < EE) absh[tid] = attn_bias_emb[tid * HH + h];
  for (int idx = tid; idx < EE * 64; idx += 256) {
    int e = idx >> 6, d = idx & 63;
    float qv = (float)qkv[(size_t)i * 1536 + h * 64 + d];
    qe[e][d] = qv * ek_tab[e * 512 + h * 64 + d];
    evh[idx] = ev_tab[e * 512 + h * 64 + d];
  }
  __syncthreads();

  for (int jl = tid; jl < n; jl += 256) {
    int e = ebuf[jl];
    const uint4* kp = (const uint4*)(qkv + (size_t)jl * 1536 + 512 + h * 64);
    uint4 kr[8];
#pragma unroll
    for (int dg = 0; dg < 8; dg++) kr[dg] = kp[dg];
    float acc = 0.f;
#pragma unroll
    for (int dg = 0; dg < 8; dg++) {
      bf16x8 kv = *reinterpret_cast<const bf16x8*>(&kr[dg]);
      f32x4 qa = *(const f32x4*)&qe[e][dg * 8];
      f32x4 qb = *(const f32x4*)&qe[e][dg * 8 + 4];
      acc += (float)kv[0] * qa.x + (float)kv[1] * qa.y + (float)kv[2] * qa.z +
             (float)kv[3] * qa.w + (float)kv[4] * qb.x + (float)kv[5] * qb.y +
             (float)kv[6] * qb.z + (float)kv[7] * qb.w;
    }
    s[jl] = acc * 0.125f + absh[e];
  }
  __syncthreads();

  float lm = -1e30f;
  for (int j = tid; j < n; j += 256) lm = fmaxf(lm, s[j]);
  lm = wave_reduce_max(lm);
  if (lane == 0) scr[wave] = lm;
  __syncthreads();
  float mx = fmaxf(fmaxf(scr[0], scr[1]), fmaxf(scr[2], scr[3]));
  float ls = 0.0f;
  for (int j = tid; j < n; j += 256) {
    float p = __expf(s[j] - mx);
    s[j] = p;
    ls += p;
  }
  ls = wave_reduce_sum(ls);
  if (lane == 0) scr[4 + wave] = ls;
  __syncthreads();
  float inv = 1.0f / (scr[4] + scr[5] + scr[6] + scr[7]);

  float acc = 0.0f;
  int j = wave;
  for (; j + 4 < n; j += 8) {
    int e0 = ebuf[j], e1 = ebuf[j + 4];
    float p0 = s[j], p1 = s[j + 4];
    float v0 = (float)qkv[(size_t)j * 1536 + 1024 + h * 64 + lane];
    float v1 = (float)qkv[(size_t)(j + 4) * 1536 + 1024 + h * 64 + lane];
    acc += p0 * v0 * evh[e0 * 64 + lane] + p1 * v1 * evh[e1 * 64 + lane];
  }
  for (; j < n; j += 4) {
    int e = ebuf[j];
    float vv = (float)qkv[(size_t)j * 1536 + 1024 + h * 64 + lane];
    acc += s[j] * vv * evh[e * 64 + lane];
  }
  red[wave * 64 + lane] = acc;
  __syncthreads();
  if (tid < 64) {
    float y = (red[tid] + red[64 + tid] + red[128 + tid] + red[192 + tid]) * inv;
    ybuf[(size_t)i * CC + h * 64 + tid] = (bf16_t)y;
  }
}

// ---------------------------------------------------------------------------
extern "C" void kernel_launch(void* const* d_in, const int* in_sizes, int n_in,
                              void* d_out, int out_size, void* d_ws,
                              size_t ws_size, hipStream_t stream) {
  const float* x = (const float*)d_in[0];
  const int* bias_mat = (const int*)d_in[1];

  char* wp = (char*)d_ws;
  float* ektab = (float*)wp;  wp += 16 * 512 * 4;
  float* evtab = (float*)wp;  wp += 16 * 512 * 4;
  float* xmu = (float*)wp;    wp += 384 * 4;
  float* xrs = (float*)wp;    wp += 384 * 4;
  float* x1s1 = (float*)wp;   wp += 384 * 4;
  float* x1s2 = (float*)wp;   wp += 384 * 4;
  float* s1q = (float*)wp;    wp += 1536 * 4;
  float* cq = (float*)wp;     wp += 1536 * 4;
  float* s1f = (float*)wp;    wp += 2048 * 4;
  float* cf = (float*)wp;     wp += 2048 * 4;
  float* x1 = (float*)wp;     wp += 384 * 512 * 4;
  bf16_t* wqkv_bf = (bf16_t*)wp;   wp += 1536 * 512 * 2;
  bf16_t* wfc_bf = (bf16_t*)wp;    wp += 2048 * 512 * 2;
  bf16_t* wproj_bf = (bf16_t*)wp;  wp += 512 * 512 * 2;
  bf16_t* wcproj_bf = (bf16_t*)wp; wp += 512 * 2048 * 2;
  bf16_t* qkv = (bf16_t*)wp;  wp += 384 * 1536 * 2;
  bf16_t* ybuf = (bf16_t*)wp; wp += 384 * 512 * 2;
  bf16_t* gbuf = (bf16_t*)wp; wp += 384 * 2048 * 2;

  PreArgs P;
  P.x = x;
  P.ln1w = (const float*)d_in[2];
  P.ln1b = (const float*)d_in[3];
  P.wattn = (const float*)d_in[4];
  P.wattnb = (const float*)d_in[5];
  P.eemb = (const float*)d_in[9];
  P.wekw = (const float*)d_in[10];
  P.wekb = (const float*)d_in[11];
  P.wevw = (const float*)d_in[12];
  P.wevb = (const float*)d_in[13];
  P.ln2w = (const float*)d_in[14];
  P.ln2b = (const float*)d_in[15];
  P.cfcw = (const float*)d_in[16];
  P.cfcb = (const float*)d_in[17];
  P.wproj = (const float*)d_in[6];
  P.wcproj = (const float*)d_in[18];
  P.ektab = ektab; P.evtab = evtab; P.xmu = xmu; P.xrs = xrs;
  P.x1s1 = x1s1; P.x1s2 = x1s2; P.s1q = s1q; P.cq = cq; P.s1f = s1f; P.cf = cf;
  P.wqkv_bf = wqkv_bf; P.wfc_bf = wfc_bf; P.wproj_bf = wproj_bf;
  P.wcproj_bf = wcproj_bf;

  // 1) tables + fused-LN weight prep + x stats + stat zeroing
  pre_k<<<1569, 256, 0, stream>>>(P);
  // 2) qkv = LN1(x) @ wattn^T + b  (fused-LN epilogue)  576 blocks
  gemm_k<0><<<dim3(48, 12), 256, 0, stream>>>(x, wqkv_bf, xmu, xrs, s1q, cq,
                                              nullptr, qkv, nullptr, nullptr,
                                              1536, 512);
  // 3) attention
  attn_k<<<dim3(TT, HH), 256, 0, stream>>>(qkv, bias_mat,
                                           (const float*)d_in[8], ektab, evtab,
                                           ybuf);
  // 4) x1 = x + y @ wproj^T + b ; accumulate x1 row stats  192 blocks
  gemm_k<1><<<dim3(16, 12), 256, 0, stream>>>(
      ybuf, wproj_bf, nullptr, nullptr, (const float*)d_in[7], nullptr, x, x1,
      x1s1, x1s2, 512, 512);
  // 5) g = gelu(LN2(x1) @ cfc^T + b)  (fused-LN epilogue)  768 blocks
  gemm_k<2><<<dim3(64, 12), 256, 0, stream>>>(x1, wfc_bf, x1s1, x1s2, s1f, cf,
                                              nullptr, gbuf, nullptr, nullptr,
                                              2048, 512);
  // 6) out = x1 + g @ cproj^T + b  192 blocks
  gemm_k<3><<<dim3(16, 12), 256, 0, stream>>>(
      gbuf, wcproj_bf, nullptr, nullptr, (const float*)d_in[19], nullptr, x1,
      d_out, nullptr, nullptr, 512, 2048);
}